// Round 1
// baseline (2808.347 us; speedup 1.0000x reference)
//
#include <hip/hip_runtime.h>
#include <cstdint>

typedef _Float16 f16;
typedef _Float16 f16x2 __attribute__((ext_vector_type(2)));

#define T_STEPS 512
#define B_SZ 512
#define LOG2PI 1.8378770664093453f

__device__ __forceinline__ uint32_t packh2(float a, float b) {
  f16x2 v; v[0] = (f16)a; v[1] = (f16)b;
  return __builtin_bit_cast(uint32_t, v);
}

__device__ __forceinline__ float fdot2(uint32_t a, uint32_t b, float c) {
#if defined(__AMDGCN__) && __has_builtin(__builtin_amdgcn_fdot2)
  return __builtin_amdgcn_fdot2(__builtin_bit_cast(f16x2, a),
                                __builtin_bit_cast(f16x2, b), c, false);
#else
  f16x2 x = __builtin_bit_cast(f16x2, a), y = __builtin_bit_cast(f16x2, b);
  return c + (float)x[0] * (float)y[0] + (float)x[1] * (float)y[1];
#endif
}

__device__ __forceinline__ float sigmoidf_(float x) {
  return 1.0f / (1.0f + __expf(-x));
}
__device__ __forceinline__ float tanhf_(float x) {
  float ax = fabsf(x);
  float t = __expf(-2.0f * ax);
  float r = (1.0f - t) / (1.0f + t);
  return copysignf(r, x);
}
__device__ __forceinline__ float softplusf_(float x) {
  return fmaxf(x, 0.0f) + __logf(1.0f + __expf(-fabsf(x)));
}

// ---------------------------------------------------------------------------
// Kernel 1: embedding / state_t construction.  state_t: (T,B,32) f16.
// ---------------------------------------------------------------------------
__global__ __launch_bounds__(256) void k_embed(
    const float* __restrict__ xs, const float* __restrict__ shot_emb,
    const float* __restrict__ player_emb, f16* __restrict__ state_t,
    float* __restrict__ accums) {
  if (blockIdx.x == 0 && threadIdx.x < 16) accums[threadIdx.x] = 0.0f;
  size_t idx = (size_t)blockIdx.x * 256 + threadIdx.x;  // (t,b) flat, exactly T*B
  const float* xp = xs + idx * 23;
  f16* op = state_t + idx * 32;
  int sid = (int)xp[12];
  int pid = (int)xp[17];
#pragma unroll
  for (int i = 0; i < 12; ++i) op[i] = (f16)xp[i];
  const float* se = shot_emb + sid * 8;
#pragma unroll
  for (int i = 0; i < 8; ++i) op[12 + i] = (f16)se[i];
#pragma unroll
  for (int i = 0; i < 4; ++i) op[20 + i] = (f16)xp[13 + i];
  const float* pe = player_emb + pid * 8;
#pragma unroll
  for (int i = 0; i < 8; ++i) op[24 + i] = (f16)pe[i];
}

// ---------------------------------------------------------------------------
// Kernel 2: backward GRU scan + encoder + qz0 head.
// 256 blocks x 512 threads, 2 batch elements per block, weights in LDS (f16).
// ---------------------------------------------------------------------------
__global__ __launch_bounds__(512) void k_gru(
    const f16* __restrict__ state_t, const float* __restrict__ wih,
    const float* __restrict__ whh, const float* __restrict__ bih,
    const float* __restrict__ bhh, const float* __restrict__ enc_w,
    const float* __restrict__ enc_b, const float* __restrict__ qz0_w,
    const float* __restrict__ qz0_b, const float* __restrict__ z0_noise,
    const float* __restrict__ pz0_mean, const float* __restrict__ pz0_logstd,
    f16* __restrict__ ctx, float* __restrict__ z0_out,
    float* __restrict__ accums) {
  __shared__ uint32_t s_whh[64 * 385];  // [kpair][row(384)] of W_hh (K=128)
  __shared__ uint32_t s_wih[16 * 385];  // K=32
  __shared__ uint32_t s_enc[64 * 65];   // enc_w, K=128, N=64
  __shared__ float s_part[4 * 2 * 2 * 128];  // [sum][ks][b][u]  (aliased epart)
  __shared__ f16 s_h[2][128];
  __shared__ f16 s_x[2][32];
  __shared__ float s_ctx0[2][64];
  __shared__ float s_q[2][32];

  const int tid = threadIdx.x;
  const int bbase = blockIdx.x * 2;

  for (int id = tid; id < 64 * 384; id += 512) {
    int kp = id % 64, n = id / 64;
    s_whh[kp * 385 + n] = packh2(whh[n * 128 + 2 * kp], whh[n * 128 + 2 * kp + 1]);
  }
  for (int id = tid; id < 16 * 384; id += 512) {
    int kp = id % 16, n = id / 16;
    s_wih[kp * 385 + n] = packh2(wih[n * 32 + 2 * kp], wih[n * 32 + 2 * kp + 1]);
  }
  for (int id = tid; id < 64 * 64; id += 512) {
    int kp = id % 64, n = id / 64;
    s_enc[kp * 65 + n] = packh2(enc_w[n * 128 + 2 * kp], enc_w[n * 128 + 2 * kp + 1]);
  }
  if (tid < 256) {
    int b = tid >> 7, u = tid & 127;
    s_h[b][u] = (f16)0.0f;
  }
  const int ks = tid >> 8;           // 0/1 : K-split
  const int du = tid & 127;          // hidden unit
  const int db = (tid >> 7) & 1;     // batch within block
  float h_old = 0.0f;
  float bR = 0, bZ = 0, bIN = 0, bHN = 0;
  if (tid < 256) {
    bR = bih[du] + bhh[du];
    bZ = bih[128 + du] + bhh[128 + du];
    bIN = bih[256 + du];
    bHN = bhh[256 + du];
  }
  float bEnc = 0.0f;
  if (tid < 128) bEnc = enc_b[tid & 63];
  if (tid >= 128 && tid < 192) {  // initial x stage for t = T-1
    int i = tid & 63;
    int b = i >> 5, ii = i & 31;
    s_x[b][ii] = state_t[((size_t)(T_STEPS - 1) * B_SZ + bbase + b) * 32 + ii];
  }
  __syncthreads();

  float* epart = s_part;  // reuse as enc partial buffer

  for (int t = T_STEPS - 1; t >= 0; --t) {
    f16 xpref = (f16)0.0f;
    if (t > 0 && tid >= 128 && tid < 192) {  // prefetch x(t-1)
      int i = tid & 63;
      int b = i >> 5, ii = i & 31;
      xpref = state_t[((size_t)(t - 1) * B_SZ + bbase + b) * 32 + ii];
    }
    // --- A: partial dot products (all 512 threads, K split by ks)
    {
      float aR = 0.0f, aZ = 0.0f, aIN = 0.0f, aHN = 0.0f;
      const uint32_t* hp = (const uint32_t*)&s_h[db][0] + ks * 32;
      const uint32_t* wb = s_whh + (ks * 32) * 385 + du;
#pragma unroll 4
      for (int i = 0; i < 32; ++i) {
        uint32_t h2 = hp[i];
        aR = fdot2(wb[i * 385], h2, aR);
        aZ = fdot2(wb[i * 385 + 128], h2, aZ);
        aHN = fdot2(wb[i * 385 + 256], h2, aHN);
      }
      const uint32_t* xp2 = (const uint32_t*)&s_x[db][0] + ks * 8;
      const uint32_t* wi = s_wih + (ks * 8) * 385 + du;
#pragma unroll
      for (int i = 0; i < 8; ++i) {
        uint32_t x2 = xp2[i];
        aR = fdot2(wi[i * 385], x2, aR);
        aZ = fdot2(wi[i * 385 + 128], x2, aZ);
        aIN = fdot2(wi[i * 385 + 256], x2, aIN);
      }
      int base = (ks * 2 + db) * 128 + du;
      s_part[base] = aR;
      s_part[512 + base] = aZ;
      s_part[1024 + base] = aIN;
      s_part[1536 + base] = aHN;
    }
    __syncthreads();
    // --- B: combine + gates (tid<256)
    if (tid < 256) {
      int b0 = (0 * 2 + db) * 128 + du, b1 = (1 * 2 + db) * 128 + du;
      float aR = s_part[b0] + s_part[b1] + bR;
      float aZ = s_part[512 + b0] + s_part[512 + b1] + bZ;
      float aIN = s_part[1024 + b0] + s_part[1024 + b1] + bIN;
      float aHN = s_part[1536 + b0] + s_part[1536 + b1] + bHN;
      float r = sigmoidf_(aR);
      float zg = sigmoidf_(aZ);
      float n = tanhf_(aIN + r * aHN);
      float hnew = (1.0f - zg) * n + zg * h_old;
      h_old = hnew;
      s_h[db][du] = (f16)hnew;
    }
    __syncthreads();
    // --- C: enc partials (all 512): (k4, eb, c)
    {
      int c = tid & 63, eb = (tid >> 6) & 1, k4 = tid >> 7;
      const uint32_t* hp = (const uint32_t*)&s_h[eb][0] + k4 * 16;
      const uint32_t* ew = s_enc + (k4 * 16) * 65 + c;
      float acc = 0.0f;
#pragma unroll
      for (int i = 0; i < 16; ++i) acc = fdot2(ew[i * 65], hp[i], acc);
      epart[k4 * 128 + eb * 64 + c] = acc;
    }
    __syncthreads();
    // --- D: enc combine + ctx write (waves 0-1); stage x(t-1) (wave 2)
    if (tid < 128) {
      int c = tid & 63, eb = tid >> 6;
      float acc = epart[eb * 64 + c] + epart[128 + eb * 64 + c] +
                  epart[256 + eb * 64 + c] + epart[384 + eb * 64 + c] + bEnc;
      ctx[((size_t)t * B_SZ + bbase + eb) * 64 + c] = (f16)acc;
      if (t == 0) s_ctx0[eb][c] = acc;
    } else if (tid < 192 && t > 0) {
      int i = tid & 63;
      int b = i >> 5, ii = i & 31;
      s_x[b][ii] = xpref;
    }
    __syncthreads();
  }
  // qz0 head: qm,qls = ctx[0] @ qz0_w.T + qz0_b  (split on output dim)
  if (tid < 64) {
    int b = tid >> 5, o = tid & 31;
    float acc = qz0_b[o];
#pragma unroll 8
    for (int k = 0; k < 64; ++k) acc += qz0_w[o * 64 + k] * s_ctx0[b][k];
    s_q[b][o] = acc;
  }
  __syncthreads();
  if (tid < 32) {
    int b = tid >> 4, l = tid & 15;
    int bg = bbase + b;
    float qm = s_q[b][l], qls = s_q[b][16 + l];
    float z0v = qm + __expf(qls) * z0_noise[bg * 16 + l];
    z0_out[bg * 16 + l] = z0v;
    float pm = pz0_mean[l], pls = pz0_logstd[l];
    float var_q = __expf(2.0f * qls);
    float var_p = __expf(2.0f * pls);
    float dm = qm - pm;
    float kl = pls - qls + (var_q + dm * dm) / (2.0f * var_p) - 0.5f;
    atomicAdd(&accums[5], kl);
  }
}

// ---------------------------------------------------------------------------
// Kernel 3: SDE Euler-Maruyama scan (511 steps), writes zs (f16), logqp_path.
// 256 blocks x 512 threads, 2 batch elements per block.
// ---------------------------------------------------------------------------
__global__ __launch_bounds__(512) void k_sde(
    const f16* __restrict__ ctx, const float* __restrict__ z0_in,
    const float* __restrict__ ts, const float* __restrict__ bm_noise,
    const float* __restrict__ fw1, const float* __restrict__ fb1,
    const float* __restrict__ fw2, const float* __restrict__ fb2,
    const float* __restrict__ fw3, const float* __restrict__ fb3,
    const float* __restrict__ hw1, const float* __restrict__ hb1,
    const float* __restrict__ hw2, const float* __restrict__ hb2,
    const float* __restrict__ hw3, const float* __restrict__ hb3,
    const float* __restrict__ gw1, const float* __restrict__ gb1,
    const float* __restrict__ gw2, const float* __restrict__ gb2,
    f16* __restrict__ zs, float* __restrict__ accums) {
  __shared__ uint32_t s_fw1[40 * 129];
  __shared__ uint32_t s_fw2[64 * 129];
  __shared__ uint32_t s_fw3[64 * 17];
  __shared__ uint32_t s_hw1[8 * 129];
  __shared__ uint32_t s_hw2[64 * 129];
  __shared__ uint32_t s_hw3[64 * 17];
  __shared__ float s_gw1[128 * 16], s_gb1[128 * 16], s_gw2[128 * 16];  // [h][l]
  __shared__ float s_fb1[128], s_fb2[128], s_fb3[16];
  __shared__ float s_hb1[128], s_hb2[128], s_hb3[16], s_gb2[16];
  __shared__ f16 s_x2[2][80];  // [z(16) | ctx(64)]
  __shared__ f16 s_fh1[2][128], s_hh1[2][128], s_fh2[2][128], s_hh2[2][128];
  __shared__ float s_zf[2][16];
  __shared__ float s_gred[2 * 16 * 8];
  __shared__ float s_gv[2][16];
  __shared__ float s_p3[512];
  __shared__ float s_v3[2][2][16];  // [mlp][b][o]

  const int tid = threadIdx.x;
  const int bbase = blockIdx.x * 2;

  for (int id = tid; id < 40 * 128; id += 512) {
    int kp = id % 40, n = id / 40;
    s_fw1[kp * 129 + n] = packh2(fw1[n * 80 + 2 * kp], fw1[n * 80 + 2 * kp + 1]);
  }
  for (int id = tid; id < 64 * 128; id += 512) {
    int kp = id % 64, n = id / 64;
    s_fw2[kp * 129 + n] = packh2(fw2[n * 128 + 2 * kp], fw2[n * 128 + 2 * kp + 1]);
    s_hw2[kp * 129 + n] = packh2(hw2[n * 128 + 2 * kp], hw2[n * 128 + 2 * kp + 1]);
  }
  for (int id = tid; id < 64 * 16; id += 512) {
    int kp = id % 64, n = id / 64;
    s_fw3[kp * 17 + n] = packh2(fw3[n * 128 + 2 * kp], fw3[n * 128 + 2 * kp + 1]);
    s_hw3[kp * 17 + n] = packh2(hw3[n * 128 + 2 * kp], hw3[n * 128 + 2 * kp + 1]);
  }
  for (int id = tid; id < 8 * 128; id += 512) {
    int kp = id % 8, n = id / 8;
    s_hw1[kp * 129 + n] = packh2(hw1[n * 16 + 2 * kp], hw1[n * 16 + 2 * kp + 1]);
  }
  for (int id = tid; id < 2048; id += 512) {
    int h = id & 127, l = id >> 7;
    s_gw1[h * 16 + l] = gw1[l * 128 + h];
    s_gb1[h * 16 + l] = gb1[l * 128 + h];
    s_gw2[h * 16 + l] = gw2[l * 128 + h];
  }
  if (tid < 128) {
    s_fb1[tid] = fb1[tid];
    s_fb2[tid] = fb2[tid];
    s_hb1[tid] = hb1[tid];
    s_hb2[tid] = hb2[tid];
  }
  if (tid < 16) {
    s_fb3[tid] = fb3[tid];
    s_hb3[tid] = hb3[tid];
    s_gb2[tid] = gb2[tid];
  }
  if (tid < 32) {
    int b = tid >> 4, l = tid & 15;
    int bg = bbase + b;
    float z = z0_in[bg * 16 + l];
    s_zf[b][l] = z;
    s_x2[b][l] = (f16)z;
    zs[(size_t)bg * 16 + l] = (f16)z;  // zs[0] = z0
  }
  f16 cpref = (f16)0.0f;
  if (tid < 128) {
    int b = tid >> 6, c = tid & 63;
    cpref = ctx[((size_t)1 * B_SZ + bbase + b) * 64 + c];  // ctx for step 0
  }
  float bm_pref = 0.0f;
  if (tid < 32) {
    int b = tid >> 4, l = tid & 15;
    bm_pref = bm_noise[((size_t)0 * B_SZ + bbase + b) * 16 + l];
  }
  float path_acc = 0.0f;
  __syncthreads();

  for (int t = 0; t < T_STEPS - 1; ++t) {
    // P0: stage ctx into x2
    if (tid < 128) {
      int b = tid >> 6, c = tid & 63;
      s_x2[b][16 + c] = cpref;
    }
    __syncthreads();
    // issue next-step prefetches (latency hidden across P1..P3)
    if (t + 1 < T_STEPS - 1) {
      if (tid < 128) {
        int b = tid >> 6, c = tid & 63;
        cpref = ctx[((size_t)(t + 2) * B_SZ + bbase + b) * 64 + c];
      }
    }
    float bm_cur = bm_pref;
    if (t + 1 < T_STEPS - 1 && tid < 32) {
      int b = tid >> 4, l = tid & 15;
      bm_pref = bm_noise[((size_t)(t + 1) * B_SZ + bbase + b) * 16 + l];
    }
    // P1: f-layer1 (waves 0-1) | h-layer1 (waves 2-3) | g partials (waves 4-7)
    if (tid < 128) {
      int b = tid >> 6, u0 = tid & 63;
      const uint32_t* xp = (const uint32_t*)&s_x2[b][0];
      float a0 = s_fb1[u0], a1 = s_fb1[u0 + 64];
#pragma unroll 4
      for (int kp = 0; kp < 40; ++kp) {
        uint32_t xv = xp[kp];
        a0 = fdot2(s_fw1[kp * 129 + u0], xv, a0);
        a1 = fdot2(s_fw1[kp * 129 + u0 + 64], xv, a1);
      }
      s_fh1[b][u0] = (f16)softplusf_(a0);
      s_fh1[b][u0 + 64] = (f16)softplusf_(a1);
    } else if (tid < 256) {
      int t2 = tid - 128;
      int b = t2 >> 6, u0 = t2 & 63;
      const uint32_t* zp = (const uint32_t*)&s_x2[b][0];  // z = first 8 pairs
      float a0 = s_hb1[u0], a1 = s_hb1[u0 + 64];
#pragma unroll
      for (int kp = 0; kp < 8; ++kp) {
        uint32_t zv = zp[kp];
        a0 = fdot2(s_hw1[kp * 129 + u0], zv, a0);
        a1 = fdot2(s_hw1[kp * 129 + u0 + 64], zv, a1);
      }
      s_hh1[b][u0] = (f16)softplusf_(a0);
      s_hh1[b][u0 + 64] = (f16)softplusf_(a1);
    } else {
      int gt = tid - 256;
      int b = gt >> 7, l = gt & 15, k8 = (gt >> 4) & 7;
      float y = s_zf[b][l];
      float acc = 0.0f;
#pragma unroll 4
      for (int i = 0; i < 16; ++i) {
        int h = k8 + 8 * i;
        float pre = y * s_gw1[h * 16 + l] + s_gb1[h * 16 + l];
        acc += softplusf_(pre) * s_gw2[h * 16 + l];
      }
      s_gred[(b * 16 + l) * 8 + k8] = acc;
    }
    __syncthreads();
    // P2: f-layer2 / h-layer2 (all 512)
    {
      int mlp = tid >> 8, b = (tid >> 7) & 1, u = tid & 127;
      const uint32_t* inp = (const uint32_t*)(mlp ? &s_hh1[b][0] : &s_fh1[b][0]);
      const uint32_t* w = mlp ? s_hw2 : s_fw2;
      float acc = mlp ? s_hb2[u] : s_fb2[u];
#pragma unroll 4
      for (int kp = 0; kp < 64; ++kp) acc = fdot2(w[kp * 129 + u], inp[kp], acc);
      f16 r = (f16)softplusf_(acc);
      if (mlp) s_hh2[b][u] = r;
      else s_fh2[b][u] = r;
    }
    __syncthreads();
    // P3: layer-3 partials (all 512): (o, b, mlp, k8)
    {
      int o = tid & 15, b = (tid >> 4) & 1, mlp = (tid >> 5) & 1, k8 = tid >> 6;
      const uint32_t* inp =
          ((const uint32_t*)(mlp ? &s_hh2[b][0] : &s_fh2[b][0])) + k8 * 8;
      const uint32_t* w = (mlp ? s_hw3 : s_fw3) + (k8 * 8) * 17 + o;
      float acc = 0.0f;
#pragma unroll
      for (int i = 0; i < 8; ++i) acc = fdot2(w[i * 17], inp[i], acc);
      s_p3[tid] = acc;
    }
    __syncthreads();
    // P3b: combine layer-3 (wave0 lanes 0-63) + g finalize (lanes 64-95)
    if (tid < 64) {
      int o = tid & 15, mlp = tid >> 5;
      int b = (tid >> 4) & 1;
      float acc = (mlp ? s_hb3[o] : s_fb3[o]);
#pragma unroll
      for (int k = 0; k < 8; ++k) acc += s_p3[k * 64 + tid];
      s_v3[mlp][b][o] = acc;
    } else if (tid < 96) {
      int gi = tid - 64;
      int b = gi >> 4, l = gi & 15;
      float acc = s_gb2[l];
#pragma unroll
      for (int k = 0; k < 8; ++k) acc += s_gred[(b * 16 + l) * 8 + k];
      s_gv[b][l] = sigmoidf_(acc);
    }
    __syncthreads();
    // P4: z update + log-ratio
    if (tid < 32) {
      int b = tid >> 4, l = tid & 15;
      int bg = bbase + b;
      float dt = ts[t + 1] - ts[t];
      float fv = s_v3[0][b][l], hv = s_v3[1][b][l], gv = s_gv[b][l];
      float u = (fv - hv) / gv;
      float lsum = u * u;
      lsum += __shfl_xor(lsum, 1);
      lsum += __shfl_xor(lsum, 2);
      lsum += __shfl_xor(lsum, 4);
      lsum += __shfl_xor(lsum, 8);
      if (l == 0) path_acc += 0.5f * lsum * dt;
      float dw = sqrtf(dt) * bm_cur;
      float zn = s_zf[b][l] + fv * dt + gv * dw;
      s_zf[b][l] = zn;
      s_x2[b][l] = (f16)zn;
      zs[((size_t)(t + 1) * B_SZ + bg) * 16 + l] = (f16)zn;
    }
    __syncthreads();
  }
  if (tid < 32 && (tid & 15) == 0) atomicAdd(&accums[6], path_acc);
}

// ---------------------------------------------------------------------------
// Kernel 4: decoder + losses.  One thread per (t,b).
// ---------------------------------------------------------------------------
__global__ __launch_bounds__(256) void k_dec(
    const f16* __restrict__ zs, const f16* __restrict__ state_t,
    const float* __restrict__ xs, const float* __restrict__ proj_w,
    const float* __restrict__ proj_b, const float* __restrict__ act_w,
    const float* __restrict__ act_b, const float* __restrict__ land_w,
    const float* __restrict__ shot_w, const float* __restrict__ move_w,
    float* __restrict__ accums) {
  __shared__ uint32_t s_proj[8 * 32];
  __shared__ uint32_t s_act[8 * 128];
  __shared__ uint32_t s_head[128 * 8];
  __shared__ float s_pb[32], s_ab[128];
  __shared__ float s_red[4 * 5];

  const int tid = threadIdx.x;
  for (int id = tid; id < 8 * 32; id += 256) {
    int kp = id & 7, n = id >> 3;
    s_proj[kp * 32 + n] = packh2(proj_w[n * 16 + 2 * kp], proj_w[n * 16 + 2 * kp + 1]);
  }
  for (int id = tid; id < 8 * 128; id += 256) {
    int kp = id & 7, n = id >> 3;
    s_act[kp * 128 + n] = packh2(act_w[n * 16 + 2 * kp], act_w[n * 16 + 2 * kp + 1]);
  }
  for (int id = tid; id < 128 * 8; id += 256) {
    int j = id >> 3, p = id & 7;
    int h0 = 2 * p, h1 = 2 * p + 1;
    float w0 = (h0 < 2) ? land_w[h0 * 128 + j]
                        : (h0 < 14 ? shot_w[(h0 - 2) * 128 + j]
                                   : move_w[(h0 - 14) * 128 + j]);
    float w1 = (h1 < 2) ? land_w[h1 * 128 + j]
                        : (h1 < 14 ? shot_w[(h1 - 2) * 128 + j]
                                   : move_w[(h1 - 14) * 128 + j]);
    s_head[j * 8 + p] = packh2(w0, w1);
  }
  if (tid < 32) s_pb[tid] = proj_b[tid];
  if (tid < 128) s_ab[tid] = act_b[tid];
  __syncthreads();

  size_t idx = (size_t)blockIdx.x * 256 + tid;  // exactly T*B threads
  uint32_t z2[8];
  const uint32_t* zp = (const uint32_t*)(zs + idx * 16);
#pragma unroll
  for (int i = 0; i < 8; ++i) z2[i] = zp[i];
  uint32_t stv[16];
  const uint32_t* stp = (const uint32_t*)(state_t + idx * 32);
#pragma unroll
  for (int i = 0; i < 16; ++i) stv[i] = stp[i];

  float sqsum = 0.0f;
#pragma unroll 4
  for (int i = 0; i < 32; ++i) {
    float acc = s_pb[i];
#pragma unroll
    for (int kp = 0; kp < 8; ++kp) acc = fdot2(s_proj[kp * 32 + i], z2[kp], acc);
    f16x2 sv = __builtin_bit_cast(f16x2, stv[i >> 1]);
    float d = (float)sv[i & 1] - acc;
    sqsum += d * d;
  }

  float hd[16];
#pragma unroll
  for (int i = 0; i < 16; ++i) hd[i] = 0.0f;
#pragma unroll 2
  for (int j = 0; j < 128; ++j) {
    float a = s_ab[j];
#pragma unroll
    for (int kp = 0; kp < 8; ++kp) a = fdot2(s_act[kp * 128 + j], z2[kp], a);
    a = fmaxf(a, 0.0f);
#pragma unroll
    for (int p = 0; p < 8; ++p) {
      f16x2 w = __builtin_bit_cast(f16x2, s_head[j * 8 + p]);
      hd[2 * p] += (float)w[0] * a;
      hd[2 * p + 1] += (float)w[1] * a;
    }
  }
  const float* xp = xs + idx * 23;
  float dl0 = hd[0] - xp[18], dl1 = hd[1] - xp[19];
  float land = dl0 * dl0 + dl1 * dl1;
  float dm0 = hd[14] - xp[21], dm1 = hd[15] - xp[22];
  float move = dm0 * dm0 + dm1 * dm1;
  int sid = (int)xp[20];
  float m = hd[2];
#pragma unroll
  for (int s = 1; s < 12; ++s) m = fmaxf(m, hd[2 + s]);
  float sume = 0.0f;
#pragma unroll
  for (int s = 0; s < 12; ++s) sume += __expf(hd[2 + s] - m);
  float lse = m + __logf(sume);
  float pl = 0.0f;
#pragma unroll
  for (int s = 0; s < 12; ++s)
    if (s == sid) pl = hd[2 + s];
  float picked = 0.0f, cnt = 0.0f;
  if (sid != 0) {
    picked = pl - lse;
    cnt = 1.0f;
  }
  float vals[5] = {sqsum, land, move, picked, cnt};
#pragma unroll
  for (int v = 0; v < 5; ++v) {
    float x = vals[v];
    for (int off = 1; off < 64; off <<= 1) x += __shfl_xor(x, off);
    vals[v] = x;
  }
  int lane = tid & 63, wv = tid >> 6;
  if (lane == 0) {
#pragma unroll
    for (int v = 0; v < 5; ++v) s_red[wv * 5 + v] = vals[v];
  }
  __syncthreads();
  if (tid == 0) {
#pragma unroll
    for (int v = 0; v < 5; ++v) {
      float s = s_red[v] + s_red[5 + v] + s_red[10 + v] + s_red[15 + v];
      atomicAdd(&accums[v], s);
    }
  }
}

// ---------------------------------------------------------------------------
// Kernel 5: finalize the two scalar outputs.
// ---------------------------------------------------------------------------
__global__ void k_fin(const float* __restrict__ accums,
                      const float* __restrict__ noise_std,
                      float* __restrict__ out) {
  if (threadIdx.x == 0 && blockIdx.x == 0) {
    float sd = noise_std[0];
    float log_pxs = -0.5f * accums[0] / (sd * sd * (float)B_SZ) -
                    (float)T_STEPS * 32.0f * (logf(sd) + 0.5f * LOG2PI);
    float land = accums[1] / (float)(T_STEPS * B_SZ * 2);
    float move = accums[2] / (float)(T_STEPS * B_SZ * 2);
    float shot = -accums[3] / fmaxf(accums[4], 1.0f);
    float out1 = accums[5] / (float)B_SZ + accums[6] / (float)B_SZ + land + shot + move;
    out[0] = log_pxs;
    out[1] = out1;
  }
}

// ---------------------------------------------------------------------------
extern "C" void kernel_launch(void* const* d_in, const int* in_sizes, int n_in,
                              void* d_out, int out_size, void* d_ws,
                              size_t ws_size, hipStream_t stream) {
  const float* xs = (const float*)d_in[1];
  const float* ts = (const float*)d_in[2];
  const float* noise_std = (const float*)d_in[3];
  const float* z0_noise = (const float*)d_in[4];
  const float* bm_noise = (const float*)d_in[5];
  const float* shot_emb = (const float*)d_in[6];
  const float* player_emb = (const float*)d_in[7];
  const float* gru_wih = (const float*)d_in[8];
  const float* gru_whh = (const float*)d_in[9];
  const float* gru_bih = (const float*)d_in[10];
  const float* gru_bhh = (const float*)d_in[11];
  const float* enc_w = (const float*)d_in[12];
  const float* enc_b = (const float*)d_in[13];
  const float* qz0_w = (const float*)d_in[14];
  const float* qz0_b = (const float*)d_in[15];
  const float* f_w1 = (const float*)d_in[16];
  const float* f_b1 = (const float*)d_in[17];
  const float* f_w2 = (const float*)d_in[18];
  const float* f_b2 = (const float*)d_in[19];
  const float* f_w3 = (const float*)d_in[20];
  const float* f_b3 = (const float*)d_in[21];
  const float* h_w1 = (const float*)d_in[22];
  const float* h_b1 = (const float*)d_in[23];
  const float* h_w2 = (const float*)d_in[24];
  const float* h_b2 = (const float*)d_in[25];
  const float* h_w3 = (const float*)d_in[26];
  const float* h_b3 = (const float*)d_in[27];
  const float* g_w1 = (const float*)d_in[28];
  const float* g_b1 = (const float*)d_in[29];
  const float* g_w2 = (const float*)d_in[30];
  const float* g_b2 = (const float*)d_in[31];
  const float* proj_w = (const float*)d_in[32];
  const float* proj_b = (const float*)d_in[33];
  const float* pz0_mean = (const float*)d_in[34];
  const float* pz0_logstd = (const float*)d_in[35];
  const float* act_w = (const float*)d_in[36];
  const float* act_b = (const float*)d_in[37];
  const float* act_land_w = (const float*)d_in[38];
  const float* act_shot_w = (const float*)d_in[39];
  const float* act_move_w = (const float*)d_in[40];

  char* ws = (char*)d_ws;
  float* accums = (float*)ws;                       // 16 floats (256 B reserved)
  f16* state_t = (f16*)(ws + 256);                  // T*B*32 f16 = 16 MB
  f16* ctx = (f16*)(ws + 256 + 16777216);           // T*B*64 f16 = 32 MB
  float* z0b = (float*)(ws + 256 + 16777216 + 33554432);   // B*16 f32
  f16* zs = (f16*)(ws + 256 + 16777216 + 33554432 + 32768);  // T*B*16 f16 = 8 MB

  k_embed<<<1024, 256, 0, stream>>>(xs, shot_emb, player_emb, state_t, accums);
  k_gru<<<256, 512, 0, stream>>>(state_t, gru_wih, gru_whh, gru_bih, gru_bhh,
                                 enc_w, enc_b, qz0_w, qz0_b, z0_noise, pz0_mean,
                                 pz0_logstd, ctx, z0b, accums);
  k_sde<<<256, 512, 0, stream>>>(ctx, z0b, ts, bm_noise, f_w1, f_b1, f_w2, f_b2,
                                 f_w3, f_b3, h_w1, h_b1, h_w2, h_b2, h_w3, h_b3,
                                 g_w1, g_b1, g_w2, g_b2, zs, accums);
  k_dec<<<1024, 256, 0, stream>>>(zs, state_t, xs, proj_w, proj_b, act_w, act_b,
                                  act_land_w, act_shot_w, act_move_w, accums);
  k_fin<<<1, 64, 0, stream>>>(accums, noise_std, (float*)d_out);
}

// Round 2
// 1999.069 us; speedup vs baseline: 1.4048x; 1.4048x over previous
//
#include <hip/hip_runtime.h>
#include <cstdint>

typedef _Float16 f16;
typedef _Float16 f16x2 __attribute__((ext_vector_type(2)));

#define T_STEPS 512
#define B_SZ 512
#define LOG2PI 1.8378770664093453f

__device__ __forceinline__ uint32_t packh2(float a, float b) {
  f16x2 v; v[0] = (f16)a; v[1] = (f16)b;
  return __builtin_bit_cast(uint32_t, v);
}

__device__ __forceinline__ float fdot2(uint32_t a, uint32_t b, float c) {
#if defined(__AMDGCN__) && __has_builtin(__builtin_amdgcn_fdot2)
  return __builtin_amdgcn_fdot2(__builtin_bit_cast(f16x2, a),
                                __builtin_bit_cast(f16x2, b), c, false);
#else
  f16x2 x = __builtin_bit_cast(f16x2, a), y = __builtin_bit_cast(f16x2, b);
  return c + (float)x[0] * (float)y[0] + (float)x[1] * (float)y[1];
#endif
}

#define DOT4(acc, w0, w1, w2, w3, v)                                     \
  do {                                                                   \
    acc = fdot2((w0), (v).x, acc); acc = fdot2((w1), (v).y, acc);        \
    acc = fdot2((w2), (v).z, acc); acc = fdot2((w3), (v).w, acc);        \
  } while (0)

__device__ __forceinline__ float sigmoidf_(float x) {
  return 1.0f / (1.0f + __expf(-x));
}
__device__ __forceinline__ float tanhf_(float x) {
  float ax = fabsf(x);
  float t = __expf(-2.0f * ax);
  float r = (1.0f - t) / (1.0f + t);
  return copysignf(r, x);
}
__device__ __forceinline__ float softplusf_(float x) {
  return fmaxf(x, 0.0f) + __logf(1.0f + __expf(-fabsf(x)));
}

// ---------------------------------------------------------------------------
// Kernel 1: embedding / state_t construction.  state_t: (T,B,32) f16.
// ---------------------------------------------------------------------------
__global__ __launch_bounds__(256) void k_embed(
    const float* __restrict__ xs, const float* __restrict__ shot_emb,
    const float* __restrict__ player_emb, f16* __restrict__ state_t,
    float* __restrict__ accums) {
  if (blockIdx.x == 0 && threadIdx.x < 16) accums[threadIdx.x] = 0.0f;
  size_t idx = (size_t)blockIdx.x * 256 + threadIdx.x;
  const float* xp = xs + idx * 23;
  f16* op = state_t + idx * 32;
  int sid = (int)xp[12];
  int pid = (int)xp[17];
#pragma unroll
  for (int i = 0; i < 12; ++i) op[i] = (f16)xp[i];
  const float* se = shot_emb + sid * 8;
#pragma unroll
  for (int i = 0; i < 8; ++i) op[12 + i] = (f16)se[i];
#pragma unroll
  for (int i = 0; i < 4; ++i) op[20 + i] = (f16)xp[13 + i];
  const float* pe = player_emb + pid * 8;
#pragma unroll
  for (int i = 0; i < 8; ++i) op[24 + i] = (f16)pe[i];
}

// ---------------------------------------------------------------------------
// Kernel 2: backward GRU scan + encoder + qz0 head.
// 256 blocks x 512 threads, 2 batch/block. Weights REGISTER-resident.
// Roles: tid<256: R/Z gate rows (g=tid>>7, du=tid&127), also h-update in B.
//        tid 256..383: N-gate rows (separate i/h accums).
//        tid 384..511: enc rows (c=e&63, ks=e>>6), also ctx combine in B.
// 2 barriers per step.
// ---------------------------------------------------------------------------
__global__ __launch_bounds__(512) void k_gru(
    const f16* __restrict__ state_t, const float* __restrict__ wih,
    const float* __restrict__ whh, const float* __restrict__ bih,
    const float* __restrict__ bhh, const float* __restrict__ enc_w,
    const float* __restrict__ enc_b, const float* __restrict__ qz0_w,
    const float* __restrict__ qz0_b, const float* __restrict__ z0_noise,
    const float* __restrict__ pz0_mean, const float* __restrict__ pz0_logstd,
    f16* __restrict__ ctx, float* __restrict__ z0_out,
    float* __restrict__ accums) {
  __shared__ uint32_t s_x[2][16];      // x_t, f16x2 packed
  __shared__ uint32_t s_h[2][64];      // h,   f16x2 packed
  __shared__ float s_gates[2 * 128 * 4];  // [b][du][R,Z,iN,hN]
  __shared__ float s_encp[2 * 64 * 2];    // [b][c][ks]
  __shared__ float s_ctx0[2][64];
  __shared__ float s_q[2][32];

  const int tid = threadIdx.x;
  const int bbase = blockIdx.x * 2;
  const uint32_t* stu = (const uint32_t*)state_t;

  uint32_t wA[64];   // whh row (RZ/N) | enc half-row (enc, 32 used)
  uint32_t wB[16];   // wih row (RZ/N)
  float bias0 = 0.f, bias1 = 0.f, encbr = 0.f;

  if (tid < 256) {
    int g = tid >> 7, du = tid & 127;
    const float* whr = whh + (size_t)(g * 128 + du) * 128;
#pragma unroll
    for (int i = 0; i < 64; ++i) wA[i] = packh2(whr[2 * i], whr[2 * i + 1]);
    const float* wxr = wih + (size_t)(g * 128 + du) * 32;
#pragma unroll
    for (int i = 0; i < 16; ++i) wB[i] = packh2(wxr[2 * i], wxr[2 * i + 1]);
    bias0 = bih[g * 128 + du] + bhh[g * 128 + du];
  } else if (tid < 384) {
    int du = tid - 256;
    const float* whr = whh + (size_t)(256 + du) * 128;
#pragma unroll
    for (int i = 0; i < 64; ++i) wA[i] = packh2(whr[2 * i], whr[2 * i + 1]);
    const float* wxr = wih + (size_t)(256 + du) * 32;
#pragma unroll
    for (int i = 0; i < 16; ++i) wB[i] = packh2(wxr[2 * i], wxr[2 * i + 1]);
    bias0 = bih[256 + du];
    bias1 = bhh[256 + du];
  } else {
    int e = tid - 384, c = e & 63, ks = e >> 6;
    const float* wer = enc_w + (size_t)c * 128 + ks * 64;
#pragma unroll
    for (int i = 0; i < 32; ++i) wA[i] = packh2(wer[2 * i], wer[2 * i + 1]);
    encbr = enc_b[c];
  }

  if (tid < 128) s_h[tid >> 6][tid & 63] = 0u;
  if (tid < 32) {
    int b = tid >> 4, i = tid & 15;
    s_x[b][i] = stu[((size_t)(T_STEPS - 1) * B_SZ + bbase + b) * 16 + i];
  }
  float h_old = 0.0f;
  __syncthreads();

  for (int t = T_STEPS - 1; t >= 0; --t) {
    uint4 xpref = make_uint4(0, 0, 0, 0);
    // ---- Phase A: gate dots (R/Z/N) + enc dots for h(t+1) + x prefetch
    if (tid < 256) {
      int g = tid >> 7, du = tid & 127;
#pragma unroll
      for (int b = 0; b < 2; ++b) {
        float a = bias0;
        const uint4* xq = (const uint4*)&s_x[b][0];
#pragma unroll
        for (int j = 0; j < 4; ++j) {
          uint4 v = xq[j];
          DOT4(a, wB[4 * j], wB[4 * j + 1], wB[4 * j + 2], wB[4 * j + 3], v);
        }
        const uint4* hq = (const uint4*)&s_h[b][0];
#pragma unroll
        for (int j = 0; j < 16; ++j) {
          uint4 v = hq[j];
          DOT4(a, wA[4 * j], wA[4 * j + 1], wA[4 * j + 2], wA[4 * j + 3], v);
        }
        s_gates[(b * 128 + du) * 4 + g] = a;
      }
    } else if (tid < 384) {
      int du = tid - 256;
#pragma unroll
      for (int b = 0; b < 2; ++b) {
        float aI = bias0, aH = bias1;
        const uint4* xq = (const uint4*)&s_x[b][0];
#pragma unroll
        for (int j = 0; j < 4; ++j) {
          uint4 v = xq[j];
          DOT4(aI, wB[4 * j], wB[4 * j + 1], wB[4 * j + 2], wB[4 * j + 3], v);
        }
        const uint4* hq = (const uint4*)&s_h[b][0];
#pragma unroll
        for (int j = 0; j < 16; ++j) {
          uint4 v = hq[j];
          DOT4(aH, wA[4 * j], wA[4 * j + 1], wA[4 * j + 2], wA[4 * j + 3], v);
        }
        s_gates[(b * 128 + du) * 4 + 2] = aI;
        s_gates[(b * 128 + du) * 4 + 3] = aH;
      }
    } else {
      int e = tid - 384, ks = e >> 6, cc = e & 63;
      (void)cc;
      if (t < T_STEPS - 1) {
#pragma unroll
        for (int b = 0; b < 2; ++b) {
          float a = 0.f;
          const uint4* hq = (const uint4*)&s_h[b][ks * 32];
#pragma unroll
          for (int j = 0; j < 8; ++j) {
            uint4 v = hq[j];
            DOT4(a, wA[4 * j], wA[4 * j + 1], wA[4 * j + 2], wA[4 * j + 3], v);
          }
          s_encp[(b * 64 + cc) * 2 + ks] = a;
        }
      }
      if (e < 8 && t > 0) {
        int b = e & 1, q = e >> 1;
        xpref = *(const uint4*)(stu +
                                ((size_t)(t - 1) * B_SZ + bbase + b) * 16 + q * 4);
      }
    }
    __syncthreads();
    // ---- Phase B: h update; ctx combine; x stage
    if (tid < 256) {
      int b = tid >> 7, du = tid & 127;
      const float4 gt = *(const float4*)&s_gates[(b * 128 + du) * 4];
      float r = sigmoidf_(gt.x), zg = sigmoidf_(gt.y);
      float n = tanhf_(gt.z + r * gt.w);
      float hnew = (1.0f - zg) * n + zg * h_old;
      h_old = hnew;
      ((f16*)&s_h[b][0])[du] = (f16)hnew;
    } else if (tid >= 384) {
      int e = tid - 384, cc = e & 63, b = e >> 6;
      if (t < T_STEPS - 1) {
        float2 p = *(const float2*)&s_encp[(b * 64 + cc) * 2];
        ctx[((size_t)(t + 1) * B_SZ + bbase + b) * 64 + cc] =
            (f16)(p.x + p.y + encbr);
      }
      if (e < 8 && t > 0) {
        int b2 = e & 1, q = e >> 1;
        *(uint4*)&s_x[b2][q * 4] = xpref;
      }
    }
    __syncthreads();
  }

  // ---- Tail: enc(h(0)) -> ctx[0] + s_ctx0; qz0 head; z0 + KL
  if (tid >= 384) {
    int e = tid - 384, ks = e >> 6, cc = e & 63;
#pragma unroll
    for (int b = 0; b < 2; ++b) {
      float a = 0.f;
      const uint4* hq = (const uint4*)&s_h[b][ks * 32];
#pragma unroll
      for (int j = 0; j < 8; ++j) {
        uint4 v = hq[j];
        DOT4(a, wA[4 * j], wA[4 * j + 1], wA[4 * j + 2], wA[4 * j + 3], v);
      }
      s_encp[(b * 64 + cc) * 2 + ks] = a;
    }
  }
  __syncthreads();
  if (tid >= 384) {
    int e = tid - 384, cc = e & 63, b = e >> 6;
    float2 p = *(const float2*)&s_encp[(b * 64 + cc) * 2];
    float val = p.x + p.y + encbr;
    ctx[((size_t)bbase + b) * 64 + cc] = (f16)val;
    s_ctx0[b][cc] = val;
  }
  __syncthreads();
  if (tid < 64) {
    int b = tid >> 5, o = tid & 31;
    float acc = qz0_b[o];
#pragma unroll 8
    for (int k = 0; k < 64; ++k) acc += qz0_w[o * 64 + k] * s_ctx0[b][k];
    s_q[b][o] = acc;
  }
  __syncthreads();
  if (tid < 32) {
    int b = tid >> 4, l = tid & 15;
    int bg = bbase + b;
    float qm = s_q[b][l], qls = s_q[b][16 + l];
    float z0v = qm + __expf(qls) * z0_noise[bg * 16 + l];
    z0_out[bg * 16 + l] = z0v;
    float pm = pz0_mean[l], pls = pz0_logstd[l];
    float var_q = __expf(2.0f * qls);
    float var_p = __expf(2.0f * pls);
    float dm = qm - pm;
    float kl = pls - qls + (var_q + dm * dm) / (2.0f * var_p) - 0.5f;
    atomicAdd(&accums[5], kl);
  }
}

// ---------------------------------------------------------------------------
// Kernel 3: SDE Euler-Maruyama scan (511 steps). Weights REGISTER-resident.
// 256 blocks x 512 threads, 2 batch/block. 5 barriers/step.
// Roles: P1: tid<256 g-partials | 256..383 f1 rows | 384..511 h1 rows
//        P2: all 512 layer-2 half-rows (mlp=tid>>8, ks=(tid>>7)&1, u=tid&127)
//        C2: all 512 combine+softplus
//        P3: tid<128 f-w3, 256..383 h-w3, 128..159 g-combine
//        P4: tid<32 z update; 32..47 ctx stage
// ---------------------------------------------------------------------------
__global__ __launch_bounds__(512) void k_sde(
    const f16* __restrict__ ctx, const float* __restrict__ z0_in,
    const float* __restrict__ ts, const float* __restrict__ bm_noise,
    const float* __restrict__ fw1, const float* __restrict__ fb1,
    const float* __restrict__ fw2, const float* __restrict__ fb2,
    const float* __restrict__ fw3, const float* __restrict__ fb3,
    const float* __restrict__ hw1, const float* __restrict__ hb1,
    const float* __restrict__ hw2, const float* __restrict__ hb2,
    const float* __restrict__ hw3, const float* __restrict__ hb3,
    const float* __restrict__ gw1, const float* __restrict__ gb1,
    const float* __restrict__ gw2, const float* __restrict__ gb2,
    f16* __restrict__ zs, float* __restrict__ accums) {
  __shared__ uint32_t s_x2[2][40];      // [z(8 u32) | ctx(32 u32)] f16x2
  __shared__ float s_zf[2][16];         // z master copy f32
  __shared__ uint32_t s_h1[2][2][64];   // [mlp][b] layer-1 act, f16x2
  __shared__ uint32_t s_h2[2][2][64];   // [mlp][b] layer-2 act, f16x2
  __shared__ float s_gp[256];           // g partials [b][l][k8]
  __shared__ float s_gv[32];            // g values   [b][l]
  __shared__ float s_p2[2 * 2 * 128 * 2];  // [mlp][b][u][ks]
  __shared__ float s_p3[2 * 2 * 16 * 8];   // [mlp][b][o][k8]
  __shared__ float s_dts[512];

  const int tid = threadIdx.x;
  const int bbase = blockIdx.x * 2;

  // ---- weight preload into registers
  uint32_t uw[48];   // g (48 f32-as-bits) | f1 (40 f16x2) | h1 (8 f16x2)
  uint32_t wP2[32];
  uint32_t wP3[8];
  float bias1r = 0.f, bias2r = 0.f, gb2r = 0.f, fb3r = 0.f, hb3r = 0.f;

  if (tid < 256) {
    int l = tid & 15, k8 = (tid >> 4) & 7;
#pragma unroll
    for (int i = 0; i < 16; ++i) {
      int h = k8 * 16 + i;
      uw[i] = __builtin_bit_cast(uint32_t, gw1[l * 128 + h]);
      uw[16 + i] = __builtin_bit_cast(uint32_t, gb1[l * 128 + h]);
      uw[32 + i] = __builtin_bit_cast(uint32_t, gw2[l * 128 + h]);
    }
  } else if (tid < 384) {
    int u = tid - 256;
    const float* w = fw1 + (size_t)u * 80;
#pragma unroll
    for (int i = 0; i < 40; ++i) uw[i] = packh2(w[2 * i], w[2 * i + 1]);
    bias1r = fb1[u];
  } else {
    int u = tid - 384;
    const float* w = hw1 + (size_t)u * 16;
#pragma unroll
    for (int i = 0; i < 8; ++i) uw[i] = packh2(w[2 * i], w[2 * i + 1]);
    bias1r = hb1[u];
  }
  {
    int u = tid & 127, ks = (tid >> 7) & 1, mlp = tid >> 8;
    const float* w = (mlp ? hw2 : fw2) + (size_t)u * 128 + ks * 64;
#pragma unroll
    for (int i = 0; i < 32; ++i) wP2[i] = packh2(w[2 * i], w[2 * i + 1]);
    bias2r = (mlp ? hb2 : fb2)[u];
  }
  if (tid < 128 || (tid >= 256 && tid < 384)) {
    int o = tid & 15, k8 = (tid >> 4) & 7;
    const float* w = ((tid >= 256) ? hw3 : fw3) + (size_t)o * 128 + k8 * 16;
#pragma unroll
    for (int i = 0; i < 8; ++i) wP3[i] = packh2(w[2 * i], w[2 * i + 1]);
  }
  if (tid >= 128 && tid < 160) gb2r = gb2[tid & 15];
  if (tid < 32) {
    fb3r = fb3[tid & 15];
    hb3r = hb3[tid & 15];
  }

  // ---- state init
  if (tid < 511) s_dts[tid] = ts[tid + 1] - ts[tid];
  float bmc = 0.f;
  uint4 cpref = make_uint4(0, 0, 0, 0);
  if (tid < 32) {
    int b = tid >> 4, l = tid & 15, bg = bbase + b;
    float z = z0_in[bg * 16 + l];
    s_zf[b][l] = z;
    ((f16*)&s_x2[b][0])[l] = (f16)z;
    zs[(size_t)bg * 16 + l] = (f16)z;
    bmc = bm_noise[((size_t)0 * B_SZ + bg) * 16 + l];
  }
  if (tid >= 32 && tid < 48) {
    int i = tid - 32, b = i & 1, q = i >> 1;
    const uint32_t* cu = (const uint32_t*)ctx;
    uint4 v = *(const uint4*)(cu + ((size_t)1 * B_SZ + bbase + b) * 32 + q * 4);
    *(uint4*)&s_x2[b][8 + q * 4] = v;
  }
  float path_acc = 0.0f;
  __syncthreads();

  for (int t = 0; t < T_STEPS - 1; ++t) {
    float bmn = 0.f;
    // ---- P1: g partials | f1 | h1 ; prefetch bm(t+1), ctx(t+2)
    if (tid < 32 && t < T_STEPS - 2) {
      int b = tid >> 4, l = tid & 15, bg = bbase + b;
      bmn = bm_noise[((size_t)(t + 1) * B_SZ + bg) * 16 + l];
    }
    if (tid >= 32 && tid < 48 && t <= T_STEPS - 3) {
      int i = tid - 32, b = i & 1, q = i >> 1;
      const uint32_t* cu = (const uint32_t*)ctx;
      cpref = *(const uint4*)(cu +
                              ((size_t)(t + 2) * B_SZ + bbase + b) * 32 + q * 4);
    }
    if (tid < 256) {
      int b = tid >> 7, l = tid & 15, k8 = (tid >> 4) & 7;
      float y = s_zf[b][l];
      float acc = 0.f;
#pragma unroll
      for (int i = 0; i < 16; ++i) {
        float pre = fmaf(y, __builtin_bit_cast(float, uw[i]),
                         __builtin_bit_cast(float, uw[16 + i]));
        acc = fmaf(softplusf_(pre), __builtin_bit_cast(float, uw[32 + i]), acc);
      }
      s_gp[(b * 16 + l) * 8 + k8] = acc;
    } else if (tid < 384) {
      int u = tid - 256;
#pragma unroll
      for (int b = 0; b < 2; ++b) {
        float a = bias1r;
        const uint4* xq = (const uint4*)&s_x2[b][0];
#pragma unroll
        for (int j = 0; j < 10; ++j) {
          uint4 v = xq[j];
          DOT4(a, uw[4 * j], uw[4 * j + 1], uw[4 * j + 2], uw[4 * j + 3], v);
        }
        ((f16*)&s_h1[0][b][0])[u] = (f16)softplusf_(a);
      }
    } else {
      int u = tid - 384;
#pragma unroll
      for (int b = 0; b < 2; ++b) {
        float a = bias1r;
        const uint4* xq = (const uint4*)&s_x2[b][0];
#pragma unroll
        for (int j = 0; j < 2; ++j) {
          uint4 v = xq[j];
          DOT4(a, uw[4 * j], uw[4 * j + 1], uw[4 * j + 2], uw[4 * j + 3], v);
        }
        ((f16*)&s_h1[1][b][0])[u] = (f16)softplusf_(a);
      }
    }
    __syncthreads();
    // ---- P2: layer-2 half-row partials (all 512)
    {
      int u = tid & 127, ks = (tid >> 7) & 1, mlp = tid >> 8;
#pragma unroll
      for (int b = 0; b < 2; ++b) {
        float a = 0.f;
        const uint4* hq = (const uint4*)&s_h1[mlp][b][ks * 32];
#pragma unroll
        for (int j = 0; j < 8; ++j) {
          uint4 v = hq[j];
          DOT4(a, wP2[4 * j], wP2[4 * j + 1], wP2[4 * j + 2], wP2[4 * j + 3], v);
        }
        s_p2[((mlp * 2 + b) * 128 + u) * 2 + ks] = a;
      }
    }
    __syncthreads();
    // ---- C2: combine + softplus (all 512)
    {
      int u = tid & 127, b = (tid >> 7) & 1, mlp = tid >> 8;
      float2 p = *(const float2*)&s_p2[((mlp * 2 + b) * 128 + u) * 2];
      ((f16*)&s_h2[mlp][b][0])[u] = (f16)softplusf_(p.x + p.y + bias2r);
    }
    __syncthreads();
    // ---- P3: layer-3 partials + g combine
    if (tid < 128 || (tid >= 256 && tid < 384)) {
      int o = tid & 15, k8 = (tid >> 4) & 7, mlp = tid >> 8;
#pragma unroll
      for (int b = 0; b < 2; ++b) {
        float a = 0.f;
        const uint4* hq = (const uint4*)&s_h2[mlp][b][k8 * 8];
#pragma unroll
        for (int j = 0; j < 2; ++j) {
          uint4 v = hq[j];
          DOT4(a, wP3[4 * j], wP3[4 * j + 1], wP3[4 * j + 2], wP3[4 * j + 3], v);
        }
        s_p3[((mlp * 2 + b) * 16 + o) * 8 + k8] = a;
      }
    } else if (tid >= 128 && tid < 160) {
      int i = tid - 128, b = i >> 4, l = i & 15;
      const float4* gp = (const float4*)&s_gp[(b * 16 + l) * 8];
      float4 g0 = gp[0], g1 = gp[1];
      float sum = g0.x + g0.y + g0.z + g0.w + g1.x + g1.y + g1.z + g1.w + gb2r;
      s_gv[b * 16 + l] = sigmoidf_(sum);
    }
    __syncthreads();
    // ---- P4: z update + log-ratio; ctx stage
    if (tid < 32) {
      int b = tid >> 4, l = tid & 15, bg = bbase + b;
      const float4* fp = (const float4*)&s_p3[((0 * 2 + b) * 16 + l) * 8];
      const float4* hp = (const float4*)&s_p3[((2 + b) * 16 + l) * 8];
      float4 f0 = fp[0], f1v = fp[1], h0 = hp[0], h1v = hp[1];
      float fv = fb3r + f0.x + f0.y + f0.z + f0.w + f1v.x + f1v.y + f1v.z + f1v.w;
      float hv = hb3r + h0.x + h0.y + h0.z + h0.w + h1v.x + h1v.y + h1v.z + h1v.w;
      float gv = s_gv[b * 16 + l];
      float dt = s_dts[t];
      float u = (fv - hv) / gv;
      float lsum = u * u;
      lsum += __shfl_xor(lsum, 1);
      lsum += __shfl_xor(lsum, 2);
      lsum += __shfl_xor(lsum, 4);
      lsum += __shfl_xor(lsum, 8);
      if (l == 0) path_acc += 0.5f * lsum * dt;
      float dw = sqrtf(dt) * bmc;
      float zn = s_zf[b][l] + fv * dt + gv * dw;
      s_zf[b][l] = zn;
      ((f16*)&s_x2[b][0])[l] = (f16)zn;
      zs[((size_t)(t + 1) * B_SZ + bg) * 16 + l] = (f16)zn;
      bmc = bmn;
    } else if (tid >= 32 && tid < 48 && t <= T_STEPS - 3) {
      int i = tid - 32, b = i & 1, q = i >> 1;
      *(uint4*)&s_x2[b][8 + q * 4] = cpref;
    }
    __syncthreads();
  }
  if (tid < 32 && (tid & 15) == 0) atomicAdd(&accums[6], path_acc);
}

// ---------------------------------------------------------------------------
// Kernel 4: decoder + losses.  One thread per (t,b).
// ---------------------------------------------------------------------------
__global__ __launch_bounds__(256) void k_dec(
    const f16* __restrict__ zs, const f16* __restrict__ state_t,
    const float* __restrict__ xs, const float* __restrict__ proj_w,
    const float* __restrict__ proj_b, const float* __restrict__ act_w,
    const float* __restrict__ act_b, const float* __restrict__ land_w,
    const float* __restrict__ shot_w, const float* __restrict__ move_w,
    float* __restrict__ accums) {
  __shared__ uint32_t s_proj[8 * 32];
  __shared__ uint32_t s_act[8 * 128];
  __shared__ uint32_t s_head[128 * 8];
  __shared__ float s_pb[32], s_ab[128];
  __shared__ float s_red[4 * 5];

  const int tid = threadIdx.x;
  for (int id = tid; id < 8 * 32; id += 256) {
    int kp = id & 7, n = id >> 3;
    s_proj[kp * 32 + n] = packh2(proj_w[n * 16 + 2 * kp], proj_w[n * 16 + 2 * kp + 1]);
  }
  for (int id = tid; id < 8 * 128; id += 256) {
    int kp = id & 7, n = id >> 3;
    s_act[kp * 128 + n] = packh2(act_w[n * 16 + 2 * kp], act_w[n * 16 + 2 * kp + 1]);
  }
  for (int id = tid; id < 128 * 8; id += 256) {
    int j = id >> 3, p = id & 7;
    int h0 = 2 * p, h1 = 2 * p + 1;
    float w0 = (h0 < 2) ? land_w[h0 * 128 + j]
                        : (h0 < 14 ? shot_w[(h0 - 2) * 128 + j]
                                   : move_w[(h0 - 14) * 128 + j]);
    float w1 = (h1 < 2) ? land_w[h1 * 128 + j]
                        : (h1 < 14 ? shot_w[(h1 - 2) * 128 + j]
                                   : move_w[(h1 - 14) * 128 + j]);
    s_head[j * 8 + p] = packh2(w0, w1);
  }
  if (tid < 32) s_pb[tid] = proj_b[tid];
  if (tid < 128) s_ab[tid] = act_b[tid];
  __syncthreads();

  size_t idx = (size_t)blockIdx.x * 256 + tid;
  uint32_t z2[8];
  const uint32_t* zp = (const uint32_t*)(zs + idx * 16);
#pragma unroll
  for (int i = 0; i < 8; ++i) z2[i] = zp[i];
  uint32_t stv[16];
  const uint32_t* stp = (const uint32_t*)(state_t + idx * 32);
#pragma unroll
  for (int i = 0; i < 16; ++i) stv[i] = stp[i];

  float sqsum = 0.0f;
#pragma unroll 4
  for (int i = 0; i < 32; ++i) {
    float acc = s_pb[i];
#pragma unroll
    for (int kp = 0; kp < 8; ++kp) acc = fdot2(s_proj[kp * 32 + i], z2[kp], acc);
    f16x2 sv = __builtin_bit_cast(f16x2, stv[i >> 1]);
    float d = (float)sv[i & 1] - acc;
    sqsum += d * d;
  }

  float hd[16];
#pragma unroll
  for (int i = 0; i < 16; ++i) hd[i] = 0.0f;
#pragma unroll 2
  for (int j = 0; j < 128; ++j) {
    float a = s_ab[j];
#pragma unroll
    for (int kp = 0; kp < 8; ++kp) a = fdot2(s_act[kp * 128 + j], z2[kp], a);
    a = fmaxf(a, 0.0f);
#pragma unroll
    for (int p = 0; p < 8; ++p) {
      f16x2 w = __builtin_bit_cast(f16x2, s_head[j * 8 + p]);
      hd[2 * p] += (float)w[0] * a;
      hd[2 * p + 1] += (float)w[1] * a;
    }
  }
  const float* xp = xs + idx * 23;
  float dl0 = hd[0] - xp[18], dl1 = hd[1] - xp[19];
  float land = dl0 * dl0 + dl1 * dl1;
  float dm0 = hd[14] - xp[21], dm1 = hd[15] - xp[22];
  float move = dm0 * dm0 + dm1 * dm1;
  int sid = (int)xp[20];
  float m = hd[2];
#pragma unroll
  for (int s = 1; s < 12; ++s) m = fmaxf(m, hd[2 + s]);
  float sume = 0.0f;
#pragma unroll
  for (int s = 0; s < 12; ++s) sume += __expf(hd[2 + s] - m);
  float lse = m + __logf(sume);
  float pl = 0.0f;
#pragma unroll
  for (int s = 0; s < 12; ++s)
    if (s == sid) pl = hd[2 + s];
  float picked = 0.0f, cnt = 0.0f;
  if (sid != 0) {
    picked = pl - lse;
    cnt = 1.0f;
  }
  float vals[5] = {sqsum, land, move, picked, cnt};
#pragma unroll
  for (int v = 0; v < 5; ++v) {
    float x = vals[v];
    for (int off = 1; off < 64; off <<= 1) x += __shfl_xor(x, off);
    vals[v] = x;
  }
  int lane = tid & 63, wv = tid >> 6;
  if (lane == 0) {
#pragma unroll
    for (int v = 0; v < 5; ++v) s_red[wv * 5 + v] = vals[v];
  }
  __syncthreads();
  if (tid == 0) {
#pragma unroll
    for (int v = 0; v < 5; ++v) {
      float s = s_red[v] + s_red[5 + v] + s_red[10 + v] + s_red[15 + v];
      atomicAdd(&accums[v], s);
    }
  }
}

// ---------------------------------------------------------------------------
// Kernel 5: finalize the two scalar outputs.
// ---------------------------------------------------------------------------
__global__ void k_fin(const float* __restrict__ accums,
                      const float* __restrict__ noise_std,
                      float* __restrict__ out) {
  if (threadIdx.x == 0 && blockIdx.x == 0) {
    float sd = noise_std[0];
    float log_pxs = -0.5f * accums[0] / (sd * sd * (float)B_SZ) -
                    (float)T_STEPS * 32.0f * (logf(sd) + 0.5f * LOG2PI);
    float land = accums[1] / (float)(T_STEPS * B_SZ * 2);
    float move = accums[2] / (float)(T_STEPS * B_SZ * 2);
    float shot = -accums[3] / fmaxf(accums[4], 1.0f);
    float out1 = accums[5] / (float)B_SZ + accums[6] / (float)B_SZ + land + shot + move;
    out[0] = log_pxs;
    out[1] = out1;
  }
}

// ---------------------------------------------------------------------------
extern "C" void kernel_launch(void* const* d_in, const int* in_sizes, int n_in,
                              void* d_out, int out_size, void* d_ws,
                              size_t ws_size, hipStream_t stream) {
  const float* xs = (const float*)d_in[1];
  const float* ts = (const float*)d_in[2];
  const float* noise_std = (const float*)d_in[3];
  const float* z0_noise = (const float*)d_in[4];
  const float* bm_noise = (const float*)d_in[5];
  const float* shot_emb = (const float*)d_in[6];
  const float* player_emb = (const float*)d_in[7];
  const float* gru_wih = (const float*)d_in[8];
  const float* gru_whh = (const float*)d_in[9];
  const float* gru_bih = (const float*)d_in[10];
  const float* gru_bhh = (const float*)d_in[11];
  const float* enc_w = (const float*)d_in[12];
  const float* enc_b = (const float*)d_in[13];
  const float* qz0_w = (const float*)d_in[14];
  const float* qz0_b = (const float*)d_in[15];
  const float* f_w1 = (const float*)d_in[16];
  const float* f_b1 = (const float*)d_in[17];
  const float* f_w2 = (const float*)d_in[18];
  const float* f_b2 = (const float*)d_in[19];
  const float* f_w3 = (const float*)d_in[20];
  const float* f_b3 = (const float*)d_in[21];
  const float* h_w1 = (const float*)d_in[22];
  const float* h_b1 = (const float*)d_in[23];
  const float* h_w2 = (const float*)d_in[24];
  const float* h_b2 = (const float*)d_in[25];
  const float* h_w3 = (const float*)d_in[26];
  const float* h_b3 = (const float*)d_in[27];
  const float* g_w1 = (const float*)d_in[28];
  const float* g_b1 = (const float*)d_in[29];
  const float* g_w2 = (const float*)d_in[30];
  const float* g_b2 = (const float*)d_in[31];
  const float* proj_w = (const float*)d_in[32];
  const float* proj_b = (const float*)d_in[33];
  const float* pz0_mean = (const float*)d_in[34];
  const float* pz0_logstd = (const float*)d_in[35];
  const float* act_w = (const float*)d_in[36];
  const float* act_b = (const float*)d_in[37];
  const float* act_land_w = (const float*)d_in[38];
  const float* act_shot_w = (const float*)d_in[39];
  const float* act_move_w = (const float*)d_in[40];

  char* ws = (char*)d_ws;
  float* accums = (float*)ws;                       // 16 floats (256 B reserved)
  f16* state_t = (f16*)(ws + 256);                  // T*B*32 f16 = 16 MB
  f16* ctx = (f16*)(ws + 256 + 16777216);           // T*B*64 f16 = 32 MB
  float* z0b = (float*)(ws + 256 + 16777216 + 33554432);   // B*16 f32
  f16* zs = (f16*)(ws + 256 + 16777216 + 33554432 + 32768);  // T*B*16 f16 = 8 MB

  k_embed<<<1024, 256, 0, stream>>>(xs, shot_emb, player_emb, state_t, accums);
  k_gru<<<256, 512, 0, stream>>>(state_t, gru_wih, gru_whh, gru_bih, gru_bhh,
                                 enc_w, enc_b, qz0_w, qz0_b, z0_noise, pz0_mean,
                                 pz0_logstd, ctx, z0b, accums);
  k_sde<<<256, 512, 0, stream>>>(ctx, z0b, ts, bm_noise, f_w1, f_b1, f_w2, f_b2,
                                 f_w3, f_b3, h_w1, h_b1, h_w2, h_b2, h_w3, h_b3,
                                 g_w1, g_b1, g_w2, g_b2, zs, accums);
  k_dec<<<1024, 256, 0, stream>>>(zs, state_t, xs, proj_w, proj_b, act_w, act_b,
                                  act_land_w, act_shot_w, act_move_w, accums);
  k_fin<<<1, 64, 0, stream>>>(accums, noise_std, (float*)d_out);
}